// Round 6
// baseline (907.443 us; speedup 1.0000x reference)
//
#include <hip/hip_runtime.h>
#include <hip/hip_bf16.h>

#define IN_DIM 64
#define BSHIFT 7                 // 128 dst nodes per bucket
#define BSIZE  128
#define CHUNK  8192              // edges per partition block
#define MAXNB1 1024              // partition LDS hist capacity
#define GT     512               // bucket_gather block size

__device__ __forceinline__ float bflo(unsigned int u) { return __uint_as_float(u << 16); }
__device__ __forceinline__ float bfhi(unsigned int u) { return __uint_as_float(u & 0xFFFF0000u); }
__device__ __forceinline__ unsigned short f2bf(float f) {
    __hip_bfloat16 b = __float2bfloat16(f);
    return *reinterpret_cast<unsigned short*>(&b);
}

// ---------------------------------------------------------------------------
// prep: v[i] = sum_k W_o[i,k] * W_att[k];  c = b_o . W_att + b_att
// ---------------------------------------------------------------------------
__global__ void prep_kernel(const float* __restrict__ W_o,
                            const float* __restrict__ b_o,
                            const float* __restrict__ W_att,
                            const float* __restrict__ b_att,
                            float* __restrict__ v,
                            float* __restrict__ c) {
    int i = threadIdx.x;
    if (i < IN_DIM) {
        float acc = 0.f;
#pragma unroll
        for (int k = 0; k < 32; ++k) acc += W_o[i * 32 + k] * W_att[k];
        v[i] = acc;
    }
    if (i == 0) {
        float acc = b_att[0];
#pragma unroll
        for (int k = 0; k < 32; ++k) acc += b_o[k] * W_att[k];
        *c = acc;
    }
}

// ---------------------------------------------------------------------------
// fused logits + partition.
// Blocks [0, 2*chunks1): partition one CHUNK of one edge type into
//   fixed-capacity bucket regions: packed[(type*NB1+bk)*CAP + rank]
//   = src | dstLocal<<17.  Bases reserved via global atomic per bucket.
// Blocks [2*chunks1, ...): logits: 16 lanes/node, float4 loads;
//   ea[n] = exp(x[n].v + c); xh = bf16(x) written as ushort4.
// ---------------------------------------------------------------------------
__global__ void logits_partition_kernel(const float* __restrict__ x,
                                        const float* __restrict__ v,
                                        const float* __restrict__ c,
                                        float* __restrict__ ea,
                                        unsigned short* __restrict__ xh, int N,
                                        const int* __restrict__ src1,
                                        const int* __restrict__ dst1,
                                        const int* __restrict__ src2,
                                        const int* __restrict__ dst2,
                                        int* __restrict__ gCtr,
                                        int* __restrict__ packed,
                                        int E, int NB1, int CAP, int chunks1) {
    __shared__ int hist[MAXNB1];
    __shared__ int base[MAXNB1];
    int pb = 2 * chunks1;
    if (blockIdx.x < pb) {
        int b = blockIdx.x;
        int type = (b >= chunks1) ? 1 : 0;
        int ci = type ? (b - chunks1) : b;
        const int* src = type ? src2 : src1;
        const int* dst = type ? dst2 : dst1;
        int e0 = ci * CHUNK;
        int e1 = min(E, e0 + CHUNK);
        for (int i = threadIdx.x; i < NB1; i += blockDim.x) hist[i] = 0;
        __syncthreads();
        for (int e = e0 + threadIdx.x; e < e1; e += blockDim.x)
            atomicAdd(&hist[dst[e] >> BSHIFT], 1);
        __syncthreads();
        for (int i = threadIdx.x; i < NB1; i += blockDim.x) {
            int h = hist[i];
            base[i] = h ? atomicAdd(&gCtr[type * NB1 + i], h) : 0;
            hist[i] = 0;  // reuse as rank counter
        }
        __syncthreads();
        for (int e = e0 + threadIdx.x; e < e1; e += blockDim.x) {
            int d = dst[e];
            int bk = d >> BSHIFT;
            int rank = base[bk] + atomicAdd(&hist[bk], 1);
            if (rank < CAP)
                packed[(size_t)(type * NB1 + bk) * CAP + rank] =
                    src[e] | ((d & (BSIZE - 1)) << 17);
        }
    } else {
        int t = (blockIdx.x - pb) * blockDim.x + threadIdx.x;
        int node = t >> 4;
        int fq = t & 15;
        if (node >= N) return;
        const float4 xv = *(const float4*)(x + (size_t)node * 64 + fq * 4);
        const float4 vv = *(const float4*)(v + fq * 4);
        ushort4 st;
        st.x = f2bf(xv.x); st.y = f2bf(xv.y); st.z = f2bf(xv.z); st.w = f2bf(xv.w);
        *(ushort4*)(xh + (size_t)node * 64 + fq * 4) = st;
        float val = xv.x * vv.x + xv.y * vv.y + xv.z * vv.z + xv.w * vv.w;
        val += __shfl_xor(val, 1);
        val += __shfl_xor(val, 2);
        val += __shfl_xor(val, 4);
        val += __shfl_xor(val, 8);
        if (fq == 0) ea[node] = expf(val + *c);
    }
}

// ---------------------------------------------------------------------------
// bucket_gather: one block per dst-bucket (128 nodes), both edge types.
// 8 waves x 8 edge-groups -> 64 edges in flight per block-iter; each group's
// 8 lanes split the 64 feats (uint4 = 8 bf16 per lane). Accumulate e*x into
// LDS num[128][65] (stride 65: in-group conflicts 2-way = free) + den[128]
// via ds float atomics. Fold type-0 into 16 regs, reset, do type-1, write.
// ---------------------------------------------------------------------------
__global__ __launch_bounds__(GT) void bucket_gather_kernel(
        const int* __restrict__ gCtr,
        const int* __restrict__ packed,
        const float* __restrict__ ea,
        const unsigned short* __restrict__ xh,
        float* __restrict__ out, int N, int NB1, int CAP) {
    __shared__ float num[BSIZE * 65];
    __shared__ float den[BSIZE];
    int nb = blockIdx.x;
    int t = threadIdx.x;
    int l = t & 63;
    int w = t >> 6;              // wave 0..7
    int g = l >> 3;              // edge group 0..7
    int fl = l & 7;              // feature-octet lane
    int dlOwn = t >> 2;          // fold ownership: dl = t>>2
    int fOwn = (t & 3) * 16;     // feats [fOwn, fOwn+16)

    float keep[16];

    for (int i = t; i < BSIZE * 65; i += GT) num[i] = 0.f;
    if (t < BSIZE) den[t] = 0.f;
    __syncthreads();

#pragma unroll
    for (int type = 0; type < 2; ++type) {
        int r = type * NB1 + nb;
        int cnt = min(gCtr[r], CAP);
        const int* seg = packed + (size_t)r * CAP;
        for (int idx = w * 8 + g; idx < cnt; idx += (GT / 64) * 8) {
            int p = seg[idx];
            int s = p & 0x1FFFF;
            int dl = p >> 17;
            float e = ea[s];
            const uint4 hv = *(const uint4*)(xh + (size_t)s * 64 + fl * 8);
            float* row = num + dl * 65 + fl * 8;
            atomicAdd(row + 0, e * bflo(hv.x));
            atomicAdd(row + 1, e * bfhi(hv.x));
            atomicAdd(row + 2, e * bflo(hv.y));
            atomicAdd(row + 3, e * bfhi(hv.y));
            atomicAdd(row + 4, e * bflo(hv.z));
            atomicAdd(row + 5, e * bfhi(hv.z));
            atomicAdd(row + 6, e * bflo(hv.w));
            atomicAdd(row + 7, e * bfhi(hv.w));
            if (fl == 0) atomicAdd(&den[dl], e);
        }
        __syncthreads();
        if (type == 0) {
            float dv = den[dlOwn];
            float inv = dv > 0.f ? 1.f / dv : 0.f;
#pragma unroll
            for (int j = 0; j < 16; ++j)
                keep[j] = num[dlOwn * 65 + fOwn + j] * inv;
            __syncthreads();
            for (int i = t; i < BSIZE * 65; i += GT) num[i] = 0.f;
            if (t < BSIZE) den[t] = 0.f;
            __syncthreads();
        }
    }

    int node = (nb << BSHIFT) + dlOwn;
    if (node < N) {
        float dv = den[dlOwn];
        float inv = dv > 0.f ? 1.f / dv : 0.f;
        float o[16];
#pragma unroll
        for (int j = 0; j < 16; ++j)
            o[j] = 0.5f * (keep[j] + num[dlOwn * 65 + fOwn + j] * inv);
        float* op = out + (size_t)node * 64 + fOwn;
        *(float4*)(op)      = make_float4(o[0], o[1], o[2], o[3]);
        *(float4*)(op + 4)  = make_float4(o[4], o[5], o[6], o[7]);
        *(float4*)(op + 8)  = make_float4(o[8], o[9], o[10], o[11]);
        *(float4*)(op + 12) = make_float4(o[12], o[13], o[14], o[15]);
    }
}

extern "C" void kernel_launch(void* const* d_in, const int* in_sizes, int n_in,
                              void* d_out, int out_size, void* d_ws, size_t ws_size,
                              hipStream_t stream) {
    const float* x     = (const float*)d_in[0];
    const float* W_o   = (const float*)d_in[1];
    const float* b_o   = (const float*)d_in[2];
    const float* W_att = (const float*)d_in[3];
    const float* b_att = (const float*)d_in[4];
    const int*   src1  = (const int*)d_in[5];
    const int*   dst1  = (const int*)d_in[6];
    const int*   src2  = (const int*)d_in[7];
    const int*   dst2  = (const int*)d_in[8];
    float* out = (float*)d_out;

    const int N = in_sizes[0] / IN_DIM;
    const int E = in_sizes[5];
    const int NB1 = (N + BSIZE - 1) >> BSHIFT;   // buckets per type
    const int avg = (E + NB1 - 1) / NB1;
    const int CAP = avg + avg / 6 + 32;          // ~ +7 sigma, P(overflow)~1e-9

    // workspace layout (64B-aligned regions)
    char* wp = (char*)d_ws;
    auto take = [&](size_t bytes) { char* p = wp; wp += (bytes + 63) & ~63ull; return p; };
    float* ea   = (float*)take((size_t)N * 4);
    float* v    = (float*)take(IN_DIM * 4);
    float* c    = (float*)take(4);
    int* gCtr   = (int*)take((size_t)2 * NB1 * 4);
    int* packed = (int*)take((size_t)2 * NB1 * CAP * 4);
    unsigned short* xh = (unsigned short*)take((size_t)N * 64 * 2);

    hipMemsetAsync(gCtr, 0, (size_t)2 * NB1 * sizeof(int), stream);

    prep_kernel<<<1, 64, 0, stream>>>(W_o, b_o, W_att, b_att, v, c);

    int chunks1 = (E + CHUNK - 1) / CHUNK;
    int logitBlocks = (N + 15) / 16;
    logits_partition_kernel<<<2 * chunks1 + logitBlocks, 256, 0, stream>>>(
        x, v, c, ea, xh, N, src1, dst1, src2, dst2, gCtr, packed,
        E, NB1, CAP, chunks1);

    bucket_gather_kernel<<<NB1, GT, 0, stream>>>(gCtr, packed, ea, xh, out,
                                                 N, NB1, CAP);
}

// Round 7
// 122.562 us; speedup vs baseline: 7.4040x; 7.4040x over previous
//
#include <hip/hip_runtime.h>
#include <hip/hip_bf16.h>

#define IN_DIM 64
#define BSHIFT 7                 // 128 dst nodes per bucket
#define BSIZE  128
#define CHUNK  8192              // edges per partition block
#define MAXNB1 1024              // partition LDS hist capacity
#define CAPMAX 1600              // static LDS capacity per bucket segment

__device__ __forceinline__ float bflo(unsigned int u) { return __uint_as_float(u << 16); }
__device__ __forceinline__ float bfhi(unsigned int u) { return __uint_as_float(u & 0xFFFF0000u); }
__device__ __forceinline__ unsigned short f2bf(float f) {
    __hip_bfloat16 b = __float2bfloat16(f);
    return *reinterpret_cast<unsigned short*>(&b);
}

// ---------------------------------------------------------------------------
// prep: v[i] = sum_k W_o[i,k] * W_att[k];  c = b_o . W_att + b_att
// ---------------------------------------------------------------------------
__global__ void prep_kernel(const float* __restrict__ W_o,
                            const float* __restrict__ b_o,
                            const float* __restrict__ W_att,
                            const float* __restrict__ b_att,
                            float* __restrict__ v,
                            float* __restrict__ c) {
    int i = threadIdx.x;
    if (i < IN_DIM) {
        float acc = 0.f;
#pragma unroll
        for (int k = 0; k < 32; ++k) acc += W_o[i * 32 + k] * W_att[k];
        v[i] = acc;
    }
    if (i == 0) {
        float acc = b_att[0];
#pragma unroll
        for (int k = 0; k < 32; ++k) acc += b_o[k] * W_att[k];
        *c = acc;
    }
}

// ---------------------------------------------------------------------------
// fused logits + partition (proven in R5).
// Blocks [0, 2*chunks1): partition one CHUNK of one edge type into
//   fixed-capacity bucket segments: packed[(type*NB1+bk)*CAP + rank]
//   = src | dstLocal<<17.
// Blocks [2*chunks1, ...): logits: 16 lanes/node, float4 loads;
//   ea[n] = exp(x[n].v + c); xh = bf16(x).
// ---------------------------------------------------------------------------
__global__ void logits_partition_kernel(const float* __restrict__ x,
                                        const float* __restrict__ v,
                                        const float* __restrict__ c,
                                        float* __restrict__ ea,
                                        unsigned short* __restrict__ xh, int N,
                                        const int* __restrict__ src1,
                                        const int* __restrict__ dst1,
                                        const int* __restrict__ src2,
                                        const int* __restrict__ dst2,
                                        int* __restrict__ gCtr,
                                        int* __restrict__ packed,
                                        int E, int NB1, int CAP, int chunks1) {
    __shared__ int hist[MAXNB1];
    __shared__ int base[MAXNB1];
    int pb = 2 * chunks1;
    if (blockIdx.x < pb) {
        int b = blockIdx.x;
        int type = (b >= chunks1) ? 1 : 0;
        int ci = type ? (b - chunks1) : b;
        const int* src = type ? src2 : src1;
        const int* dst = type ? dst2 : dst1;
        int e0 = ci * CHUNK;
        int e1 = min(E, e0 + CHUNK);
        for (int i = threadIdx.x; i < NB1; i += blockDim.x) hist[i] = 0;
        __syncthreads();
        for (int e = e0 + threadIdx.x; e < e1; e += blockDim.x)
            atomicAdd(&hist[dst[e] >> BSHIFT], 1);
        __syncthreads();
        for (int i = threadIdx.x; i < NB1; i += blockDim.x) {
            int h = hist[i];
            base[i] = h ? atomicAdd(&gCtr[type * NB1 + i], h) : 0;
            hist[i] = 0;  // reuse as rank counter
        }
        __syncthreads();
        for (int e = e0 + threadIdx.x; e < e1; e += blockDim.x) {
            int d = dst[e];
            int bk = d >> BSHIFT;
            int rank = base[bk] + atomicAdd(&hist[bk], 1);
            if (rank < CAP)
                packed[(size_t)(type * NB1 + bk) * CAP + rank] =
                    src[e] | ((d & (BSIZE - 1)) << 17);
        }
    } else {
        int t = (blockIdx.x - pb) * blockDim.x + threadIdx.x;
        int node = t >> 4;
        int fq = t & 15;
        if (node >= N) return;
        const float4 xv = *(const float4*)(x + (size_t)node * 64 + fq * 4);
        const float4 vv = *(const float4*)(v + fq * 4);
        ushort4 st;
        st.x = f2bf(xv.x); st.y = f2bf(xv.y); st.z = f2bf(xv.z); st.w = f2bf(xv.w);
        *(ushort4*)(xh + (size_t)node * 64 + fq * 4) = st;
        float val = xv.x * vv.x + xv.y * vv.y + xv.z * vv.z + xv.w * vv.w;
        val += __shfl_xor(val, 1);
        val += __shfl_xor(val, 2);
        val += __shfl_xor(val, 4);
        val += __shfl_xor(val, 8);
        if (fq == 0) ea[node] = expf(val + *c);
    }
}

// ---------------------------------------------------------------------------
// csr_gather: one block per 128-node bucket; fused fine-CSR + gather.
// Phase A (per type): LDS hist by dstLocal (int atomics), 128-wide scan,
//   reorder edge src-ids into eord[] and cache ea[src] into eav[] (LDS).
// Phase B: 8 waves x 16 nodes each; per node: 8 edge-groups x 8 feat-lanes,
//   register accumulation (R4's proven loop), edges + ea read from LDS.
// ---------------------------------------------------------------------------
__global__ __launch_bounds__(512) void csr_gather_kernel(
        const int* __restrict__ gCtr,
        const int* __restrict__ packed,
        const float* __restrict__ ea,
        const unsigned short* __restrict__ xh,
        float* __restrict__ out, int N, int NB1, int CAP) {
    __shared__ int   eord[2][CAPMAX];
    __shared__ float eav [2][CAPMAX];
    __shared__ int hist[2][BSIZE];
    __shared__ int exv [2][BSIZE];
    __shared__ int cur [BSIZE];
    int nb = blockIdx.x;
    int t = threadIdx.x;

    // ---- Phase A: build LDS CSR for both types ----
#pragma unroll
    for (int type = 0; type < 2; ++type) {
        int r = type * NB1 + nb;
        int cnt = min(gCtr[r], CAP);
        const int* seg = packed + (size_t)r * CAP;
        if (t < BSIZE) hist[type][t] = 0;
        __syncthreads();
        for (int i = t; i < cnt; i += 512)
            atomicAdd(&hist[type][seg[i] >> 17], 1);
        __syncthreads();
        // exclusive scan over 128 bins (Hillis-Steele, cur as temp)
        int v = 0, val = 0;
        if (t < BSIZE) { v = hist[type][t]; val = v; cur[t] = v; }
        __syncthreads();
        for (int off = 1; off < BSIZE; off <<= 1) {
            int u = 0;
            if (t < BSIZE && t >= off) u = cur[t - off];
            __syncthreads();
            if (t < BSIZE) { val += u; cur[t] = val; }
            __syncthreads();
        }
        if (t < BSIZE) { exv[type][t] = val - v; cur[t] = val - v; }
        __syncthreads();
        for (int i = t; i < cnt; i += 512) {
            int p = seg[i];
            int dl = p >> 17;
            int s = p & 0x1FFFF;
            int pos = atomicAdd(&cur[dl], 1);
            eord[type][pos] = s;
            eav[type][pos] = ea[s];
        }
        __syncthreads();
    }

    // ---- Phase B: per-node register gather ----
    int l = t & 63;
    int w = t >> 6;              // wave 0..7
    int g = l >> 3;              // edge group 0..7
    int fl = l & 7;              // feature-octet lane

    for (int ni = 0; ni < 16; ++ni) {
        int dl = w * 16 + ni;
        float rr[8] = {0.f, 0.f, 0.f, 0.f, 0.f, 0.f, 0.f, 0.f};
#pragma unroll
        for (int type = 0; type < 2; ++type) {
            int k0 = exv[type][dl];
            int deg = hist[type][dl];
            if (deg <= 0) continue;
            float a[8] = {0.f, 0.f, 0.f, 0.f, 0.f, 0.f, 0.f, 0.f};
            float ew = 0.f;
            for (int j = g; j < deg; j += 8) {
                int s = eord[type][k0 + j];
                float e = eav[type][k0 + j];
                ew += e;
                const uint4 hv = *(const uint4*)(xh + (size_t)s * 64 + (fl << 3));
                a[0] = fmaf(e, bflo(hv.x), a[0]);
                a[1] = fmaf(e, bfhi(hv.x), a[1]);
                a[2] = fmaf(e, bflo(hv.y), a[2]);
                a[3] = fmaf(e, bfhi(hv.y), a[3]);
                a[4] = fmaf(e, bflo(hv.z), a[4]);
                a[5] = fmaf(e, bfhi(hv.z), a[5]);
                a[6] = fmaf(e, bflo(hv.w), a[6]);
                a[7] = fmaf(e, bfhi(hv.w), a[7]);
            }
            ew += __shfl_xor(ew, 8); ew += __shfl_xor(ew, 16); ew += __shfl_xor(ew, 32);
            float inv = 1.f / ew;
#pragma unroll
            for (int k = 0; k < 8; ++k) rr[k] += a[k] * inv;
        }
#pragma unroll
        for (int k = 0; k < 8; ++k) {
            rr[k] += __shfl_xor(rr[k], 8);
            rr[k] += __shfl_xor(rr[k], 16);
            rr[k] += __shfl_xor(rr[k], 32);
        }
        int node = (nb << BSHIFT) + dl;
        if (node < N && l < 8) {
            float* op = out + (size_t)node * 64 + l * 8;
            *(float4*)op       = make_float4(0.5f * rr[0], 0.5f * rr[1], 0.5f * rr[2], 0.5f * rr[3]);
            *(float4*)(op + 4) = make_float4(0.5f * rr[4], 0.5f * rr[5], 0.5f * rr[6], 0.5f * rr[7]);
        }
    }
}

extern "C" void kernel_launch(void* const* d_in, const int* in_sizes, int n_in,
                              void* d_out, int out_size, void* d_ws, size_t ws_size,
                              hipStream_t stream) {
    const float* x     = (const float*)d_in[0];
    const float* W_o   = (const float*)d_in[1];
    const float* b_o   = (const float*)d_in[2];
    const float* W_att = (const float*)d_in[3];
    const float* b_att = (const float*)d_in[4];
    const int*   src1  = (const int*)d_in[5];
    const int*   dst1  = (const int*)d_in[6];
    const int*   src2  = (const int*)d_in[7];
    const int*   dst2  = (const int*)d_in[8];
    float* out = (float*)d_out;

    const int N = in_sizes[0] / IN_DIM;
    const int E = in_sizes[5];
    const int NB1 = (N + BSIZE - 1) >> BSHIFT;   // buckets per type
    const int avg = (E + NB1 - 1) / NB1;
    int CAP = avg + avg / 6 + 32;                // ~ +7 sigma, P(overflow)~1e-9
    if (CAP > CAPMAX) CAP = CAPMAX;

    // workspace layout (64B-aligned regions)
    char* wp = (char*)d_ws;
    auto take = [&](size_t bytes) { char* p = wp; wp += (bytes + 63) & ~63ull; return p; };
    float* ea   = (float*)take((size_t)N * 4);
    float* v    = (float*)take(IN_DIM * 4);
    float* c    = (float*)take(4);
    int* gCtr   = (int*)take((size_t)2 * NB1 * 4);
    int* packed = (int*)take((size_t)2 * NB1 * CAP * 4);
    unsigned short* xh = (unsigned short*)take((size_t)N * 64 * 2);

    hipMemsetAsync(gCtr, 0, (size_t)2 * NB1 * sizeof(int), stream);

    prep_kernel<<<1, 64, 0, stream>>>(W_o, b_o, W_att, b_att, v, c);

    int chunks1 = (E + CHUNK - 1) / CHUNK;
    int logitBlocks = (N + 15) / 16;
    logits_partition_kernel<<<2 * chunks1 + logitBlocks, 256, 0, stream>>>(
        x, v, c, ea, xh, N, src1, dst1, src2, dst2, gCtr, packed,
        E, NB1, CAP, chunks1);

    csr_gather_kernel<<<NB1, 512, 0, stream>>>(gCtr, packed, ea, xh, out,
                                               N, NB1, CAP);
}